// Round 7
// baseline (2827.086 us; speedup 1.0000x reference)
//
#include <hip/hip_runtime.h>

// Problem constants
#define BSZ  128
#define TT   50
#define CIN  2312
#define HID  300
#define NOUT 10
#define KS   5
#define T1   51          // (TT+5) - KS + 1
#define T2   52          // (T1+5) - KS + 1
#define NCH  289         // CIN / 8
#define OTW  10          // o-tiles of 32

typedef unsigned int u32;

// exp(-k^2/8), k=1..4
#define EK1 0.88249690258459546
#define EK2 0.60653065971263342
#define EK3 0.32465246735834974
#define EK4 0.13533528323661270

__device__ __forceinline__ void gauss5(double w, double p, double* e5) {
  const double c = p + 2.0;                  // P + MAX_DELAY//2
  // e_k = exp(-(k-c)^2/8) = E0 * U^k * exp(-k^2/8)
  const double E0 = ::exp(c * c * (-0.125));
  const double U  = ::exp(c * 0.25);
  const double u2 = U * U;
  const double e0 = E0;
  const double e1 = E0 * U * EK1;
  const double e2 = E0 * u2 * EK2;
  const double e3 = E0 * (u2 * U) * EK3;
  const double e4 = E0 * (u2 * u2) * EK4;
  const double inv = 1.0 / (((((e0 + e1) + e2) + e3) + e4) + 1e-7);
  e5[0] = w * (e0 * inv); e5[1] = w * (e1 * inv); e5[2] = w * (e2 * inv);
  e5[3] = w * (e3 * inv); e5[4] = w * (e4 * inv);
}

// ---------------------------------------------------------------------------
// Precompute B taps to global: Bg[(ow*289+c)*1280 + (k*8+isub)*32 + o]
// ---------------------------------------------------------------------------
__global__ __launch_bounds__(256) void build_B(
    const float* __restrict__ W1, const float* __restrict__ P1,
    double* __restrict__ Bg) {
  const int blk = blockIdx.x;                // ow*289 + c
  const int ow = blk / NCH, c = blk % NCH;
  const int tid = threadIdx.x;
  const int o = tid & 31, isub = tid >> 5;   // 1 cell/thread
  const int bo = ow * 32 + o;
  double w = 0.0, p = 0.0;
  if (bo < HID) {
    const size_t gi = (size_t)bo * CIN + c * 8 + isub;
    w = (double)W1[gi]; p = (double)P1[gi];
  }
  double e5[KS];
  gauss5(w, p, e5);
  double* dst = Bg + (size_t)blk * 1280;
#pragma unroll
  for (int k = 0; k < KS; ++k) dst[(k * 8 + isub) * 32 + o] = e5[k];
}

// ---------------------------------------------------------------------------
// Layer-1: fp64 GEMM 51t x 32o x (CIN*5), double-buffered LDS, then fp64 LIF
// scan + ballot bit-pack. Grid (10, 128) = 1280 blocks = 5/CU exact.
// LDS doubles: Bsd[2][1280] at [0,2560), Asd[2][8][64] at [2560,3584).
// y1s[51][32] overlays [0,1632) after the loop.
// FUSED=1: synthesize B in-loop (no Bg). FUSED=0: stage B from Bg.
// ---------------------------------------------------------------------------
template<int FUSED>
__global__ __launch_bounds__(256) void snn_l1_t(
    const float* __restrict__ data, const float* __restrict__ W1,
    const float* __restrict__ P1, const float* __restrict__ b1v,
    const double* __restrict__ Bg, u32* __restrict__ gbits)
{
  __shared__ double dsm[3584];               // 28672 B
  double* Bsd = dsm;                         // [2][1280]
  double* Asd = dsm + 2560;                  // [2][512] = [2][8][64]

  const int ow = blockIdx.x, b = blockIdx.y;
  const int tid = threadIdx.x;
  const float* abase = data + (size_t)b * (TT * CIN);

  const int ty  = tid >> 5;                  // 0..7
  const int col = tid & 31;                  // 0..31
  const int r0  = 7 * ty;                    // rows r0..r0+6 (51 valid of 56)

  // A-staging map: 224 threads, slot-major (conflict-free)
  const int apair = tid / 56;                // 0..3 -> i-subs {2p, 2p+1}
  const int aslot = tid % 56;                // 0..55 (slot = t + k)

  double acc[7];
#pragma unroll
  for (int r = 0; r < 7; ++r) acc[r] = 0.0;

  // macro-hygiene: only `cc_` / `buf_` / locals with trailing underscore here
#define STAGE(cc_, buf_)                                                      \
  {                                                                           \
    if (tid < 224) {                                                          \
      const int tp_ = aslot - 5;                                              \
      float2 v_ = make_float2(0.f, 0.f);                                      \
      if (tp_ >= 0)                                                           \
        v_ = *(const float2*)(abase + (size_t)tp_ * CIN + (cc_) * 8 + 2 * apair);\
      Asd[(buf_) * 512 + (2 * apair) * 64 + aslot]     = (double)v_.x;        \
      Asd[(buf_) * 512 + (2 * apair + 1) * 64 + aslot] = (double)v_.y;        \
    } else {                                                                  \
      const int z_ = tid - 224;              /* zero pad slots 56..63 */      \
      Asd[(buf_) * 512 + (z_ >> 2) * 64 + 56 + 2 * (z_ & 3)]     = 0.0;       \
      Asd[(buf_) * 512 + (z_ >> 2) * 64 + 56 + 2 * (z_ & 3) + 1] = 0.0;       \
    }                                                                         \
    if (FUSED) {                                                              \
      const int bo_ = ow * 32 + col;                                          \
      double w_ = 0.0, p_ = 0.0;                                              \
      if (bo_ < HID) {                                                        \
        const size_t gi_ = (size_t)bo_ * CIN + (cc_) * 8 + ty;                \
        w_ = (double)W1[gi_]; p_ = (double)P1[gi_];                           \
      }                                                                       \
      double e5_[KS];                                                         \
      gauss5(w_, p_, e5_);                                                    \
      _Pragma("unroll")                                                       \
      for (int k_ = 0; k_ < KS; ++k_)                                         \
        Bsd[(buf_) * 1280 + (k_ * 8 + ty) * 32 + col] = e5_[k_];              \
    } else {                                                                  \
      const double* src_ = Bg + ((size_t)(ow * NCH + (cc_))) * 1280;          \
      _Pragma("unroll")                                                       \
      for (int j_ = 0; j_ < 5; ++j_)                                          \
        Bsd[(buf_) * 1280 + tid + 256 * j_] = src_[tid + 256 * j_];           \
    }                                                                         \
  }

  STAGE(0, 0);
  __syncthreads();

  for (int c = 0; c < NCH; ++c) {
    const int pb = c & 1;
    if (c + 1 < NCH) STAGE(c + 1, pb ^ 1);

    const double* As_ = Asd + pb * 512;
    const double* Bs_ = Bsd + pb * 1280;
#pragma unroll
    for (int kk = 0; kk < 8; ++kk) {
      double a[11];
#pragma unroll
      for (int j = 0; j < 11; ++j) a[j] = As_[kk * 64 + r0 + j];
      double bq[KS];
#pragma unroll
      for (int k = 0; k < KS; ++k) bq[k] = Bs_[(k * 8 + kk) * 32 + col];
#pragma unroll
      for (int k = 0; k < KS; ++k)
#pragma unroll
        for (int r = 0; r < 7; ++r)
          acc[r] = fma(a[k + r], bq[k], acc[r]);
    }
    __syncthreads();
  }
#undef STAGE

  // ---- y1 tile -> LDS (overlays Bsd; fenced by loop-final barrier) ----
  double* y1s = dsm;                         // [51][32]
#pragma unroll
  for (int r = 0; r < 7; ++r) {
    const int row = r0 + r;
    if (row < T1) y1s[row * 32 + col] = acc[r];
  }
  __syncthreads();

  // ---- fp64 LIF scan on lanes 0..31 + ballot bit-pack ----
  if (tid < 32) {
    const int o = ow * 32 + tid;
    const bool valid = o < HID;
    const double bias = valid ? (double)b1v[o] : 0.0;
    u32* bits = gbits + (size_t)b * 510;
    double mem = 0.0;
    for (int t = 0; t < T1; ++t) {
      const double x = y1s[t * 32 + tid] + bias;
      const double reset = (mem > 1.0) ? 1.0 : 0.0;
      mem = __dsub_rn(__dadd_rn(__dmul_rn(0.9, mem), x), reset);
      const unsigned long long mk = __ballot(valid && (mem > 1.0));
      if (tid == 0) bits[t * 10 + ow] = (u32)mk;   // lanes 32..63 inactive -> 0
    }
  }
}

// ---------------------------------------------------------------------------
// Layer-2 conv + LIF2 (fp32) from bit-packed spikes. Unchanged (not hot).
// smem floats: [0,15000) K2s, [15000,15510) lbits u32, [15510,16030) y2s.
// ---------------------------------------------------------------------------
__global__ __launch_bounds__(256) void snn_l2k(
    const u32* __restrict__ gbits,
    const float* __restrict__ W2, const float* __restrict__ P2,
    const float* __restrict__ b2, float* __restrict__ out)
{
  __shared__ float smem[16030];
  const int b = blockIdx.x, tid = threadIdx.x;
  float* K2s = smem;
  u32* lbits = (u32*)(smem + 15000);
  float* y2s = smem + 15510;

  for (int i = tid; i < 510; i += 256) lbits[i] = gbits[(size_t)b * 510 + i];

  for (int idx = tid; idx < NOUT * HID; idx += 256) {
    const int o = idx / HID, i = idx % HID;
    const float w = W2[idx], p = P2[idx];
    const float c = p + 2.0f;
    float e[KS], s = 0.f;
#pragma unroll
    for (int k = 0; k < KS; ++k) {
      const float d = ((float)k - c) * 0.5f;
      e[k] = __expf(-0.5f * d * d);
      s += e[k];
    }
    const float denom = s + 1e-7f;
#pragma unroll
    for (int k = 0; k < KS; ++k)
      K2s[(o * KS + k) * HID + i] = w * (e[k] / denom);
  }
  __syncthreads();

  for (int task = tid; task < T2 * NOUT; task += 256) {
    const int t2 = task / NOUT, o = task % NOUT;
    float acc = b2[o];
#pragma unroll
    for (int k = 0; k < KS; ++k) {
      const int tp = t2 + k - KS;
      if (tp < 0 || tp >= T1) continue;
      const float* kr = K2s + (o * KS + k) * HID;
      const u32* br = (const u32*)lbits + tp * 10;
      for (int i = 0; i < HID; ++i)
        acc = fmaf((float)((br[i >> 5] >> (i & 31)) & 1u), kr[i], acc);
    }
    y2s[task] = acc;
  }
  __syncthreads();

  if (tid < NOUT) {
    float mem = 0.f;
    for (int t = 0; t < T2; ++t) {
      const float x = y2s[t * NOUT + tid];
      const float reset = (mem > 1.0f) ? 1.0f : 0.0f;
      mem = __fsub_rn(__fadd_rn(__fmul_rn(0.9f, mem), x), reset);
      out[(size_t)t * (BSZ * NOUT) + b * NOUT + tid] = (mem > 1.0f) ? 1.0f : 0.0f;
      out[(size_t)T2 * BSZ * NOUT + (size_t)t * (BSZ * NOUT) + b * NOUT + tid] = mem;
    }
  }
}

// ---------------- launcher --------------------------------------------------
extern "C" void kernel_launch(void* const* d_in, const int* in_sizes, int n_in,
                              void* d_out, int out_size, void* d_ws, size_t ws_size,
                              hipStream_t stream) {
  const float* data = (const float*)d_in[0];
  const float* W1   = (const float*)d_in[1];
  const float* P1   = (const float*)d_in[2];
  const float* b1v  = (const float*)d_in[3];
  const float* W2   = (const float*)d_in[4];
  const float* P2   = (const float*)d_in[5];
  const float* b2   = (const float*)d_in[6];
  float* out = (float*)d_out;

  const size_t BG_BYTES   = (size_t)OTW * NCH * 1280 * sizeof(double); // 29,593,600
  const size_t BITS_BYTES = (size_t)BSZ * T1 * 10 * sizeof(u32);       //    261,120

  if (ws_size >= BG_BYTES + BITS_BYTES) {
    // Mode P: precompute B to global, synthesis-free hot loop
    double* Bg = (double*)d_ws;
    u32* gbits = (u32*)((char*)d_ws + BG_BYTES);
    build_B<<<OTW * NCH, 256, 0, stream>>>(W1, P1, Bg);
    snn_l1_t<0><<<dim3(OTW, BSZ), 256, 0, stream>>>(data, W1, P1, b1v, Bg, gbits);
    snn_l2k<<<BSZ, 256, 0, stream>>>(gbits, W2, P2, b2, out);
  } else {
    // Mode F: fused in-loop synthesis (ws >= bits is established fact)
    u32* gbits = (u32*)d_ws;
    snn_l1_t<1><<<dim3(OTW, BSZ), 256, 0, stream>>>(data, W1, P1, b1v, nullptr, gbits);
    snn_l2k<<<BSZ, 256, 0, stream>>>(gbits, W2, P2, b2, out);
  }
}